// Round 8
// baseline (583.718 us; speedup 1.0000x reference)
//
#include <hip/hip_runtime.h>

typedef __bf16 bf16;
typedef __bf16 bf16x8 __attribute__((ext_vector_type(8)));
typedef __bf16 bf16x4 __attribute__((ext_vector_type(4)));
typedef float floatx4 __attribute__((ext_vector_type(4)));

#define T_TOK 8192          // B*S tokens
#define SEQ 2048
#define KLD 584             // padded Kp leading dim (1168 B rows)
#define SM_SCALE 0.07216878364870323f   // 192^-0.5
#define NJOBS 768           // attn jobs: 4 b x 3 g x 64 q-macro32

// async global->LDS, 16B per lane; LDS dest is wave-uniform base + lane*16 (linear),
// global source address is per-lane.
__device__ __forceinline__ void dma16(const void* g, void* l) {
  __builtin_amdgcn_global_load_lds(
      (const __attribute__((address_space(1))) unsigned int*)g,
      (__attribute__((address_space(3))) unsigned int*)l, 16, 0, 0);
}

// Raw barrier pair WITHOUT a "memory" clobber (v10's clobber forced the compiler to
// rematerialize the persistent Q fragments from global EVERY k-iteration: VGPR_Count
// 116 < 144 needed for qf; FETCH 355MB). m201 pattern: sched_barrier(0) fences pin
// the DS-op ordering around the barrier (rule 18); no clobber -> qf stays in VGPRs.
__device__ __forceinline__ void sync_vm() {   // DMA handoff: all VMEM drained, then rendezvous
  __builtin_amdgcn_sched_barrier(0);
  asm volatile("s_waitcnt vmcnt(0) lgkmcnt(0)");
  __builtin_amdgcn_s_barrier();
  __builtin_amdgcn_sched_barrier(0);
}
__device__ __forceinline__ void sync_lg() {   // LDS visibility: Ps/alpha writes complete
  __builtin_amdgcn_sched_barrier(0);
  asm volatile("s_waitcnt lgkmcnt(0)");
  __builtin_amdgcn_s_barrier();
  __builtin_amdgcn_sched_barrier(0);
}

// ============================ prep kernels ============================
__global__ __launch_bounds__(256) void cast_f32_bf16(const float* __restrict__ in,
                                                     bf16* __restrict__ out, long n4) {
  long i = (long)blockIdx.x * 256 + threadIdx.x;
  if (i >= n4) return;
  float4 v = ((const float4*)in)[i];
  bf16x4 o;
  o[0] = (bf16)v.x; o[1] = (bf16)v.y; o[2] = (bf16)v.z; o[3] = (bf16)v.w;
  ((bf16x4*)out)[i] = o;
}

// wkv_a (576,1024) -> bf16 padded to (640,1024), pad rows zeroed
__global__ __launch_bounds__(256) void cast_wkva_pad(const float* __restrict__ in,
                                                     bf16* __restrict__ out) {
  long i = (long)blockIdx.x * 256 + threadIdx.x;   // 4-elem chunks, 640*256 total
  int r = (int)(i >> 8);
  bf16x4 o;
  if (r < 576) {
    float4 v = ((const float4*)in)[i];
    o[0] = (bf16)v.x; o[1] = (bf16)v.y; o[2] = (bf16)v.z; o[3] = (bf16)v.w;
  } else {
    o[0] = (bf16)0.f; o[1] = (bf16)0.f; o[2] = (bf16)0.f; o[3] = (bf16)0.f;
  }
  ((bf16x4*)out)[i] = o;
}

// wkv_b (12*256, 512): d<128 -> wbnT[h][c][d] (transposed), d>=128 -> wbv[h][d-128][c]
// also zeroes the attn job counter (stream-ordered well before mla_attn)
__global__ __launch_bounds__(256) void split_wkvb(const float* __restrict__ in,
                                                  bf16* __restrict__ wbnT,
                                                  bf16* __restrict__ wbv,
                                                  int* __restrict__ ctr) {
  if (blockIdx.x == 0 && threadIdx.x == 0) *ctr = 0;
  int i = blockIdx.x * 256 + threadIdx.x;          // < 12*256*512
  int h = i >> 17, rem = i & 131071, d = rem >> 9, c = rem & 511;
  bf16 v = (bf16)in[i];
  if (d < 128) wbnT[((h * 512 + c) << 7) + d] = v;
  else         wbv[((h * 128 + (d - 128)) << 9) + c] = v;
}

// ============================ GEMM: C[M,N] = A[M,K] * B[N,K]^T ============================
// Staging via global_load_lds (m97 pattern). MODE 0: fp32 C. MODE 1: bf16 C.
// MODE 2: q-epilogue (rope q_pe -> qabs, scale q_nope -> qn).
// MODE 3: bf16 C^T via LDS transpose (coalesced 8B stores, was 2B scatter).
template <int MODE>
__global__ __launch_bounds__(256) void gemm_bt(
    const bf16* __restrict__ A, const bf16* __restrict__ B, void* __restrict__ Cv,
    int N, int K, int lda, int ldb, int ldc,
    long sA, long sB, long sC,
    const float* __restrict__ freqs, bf16* __restrict__ qn, bf16* __restrict__ qabs) {
  __shared__ alignas(16) bf16 As[128 * 32];
  __shared__ alignas(16) bf16 Bs[128 * 32];
  const int z = blockIdx.z;
  A += (long)z * sA;  B += (long)z * sB;
  const int row0 = blockIdx.y * 128, col0 = blockIdx.x * 128;
  const int tid = threadIdx.x;
  const int w = tid >> 6, l = tid & 63, lm = l & 15, quad = l >> 4;
  const int wr = w >> 1, wc = w & 1;
  floatx4 acc[4][4] = {};

  // per-lane source geometry for dma16 staging: chunk ch covers rows 16ch..16ch+15,
  // lane l -> row 16ch + (l>>2), elem col (l&3)*8 (16B per lane, LDS linear)
  const int srow = l >> 2, scol = (l & 3) * 8;

  for (int k0 = 0; k0 < K; k0 += 32) {
    __syncthreads();
#pragma unroll
    for (int c = 0; c < 2; c++) {
      const int ch = w * 2 + c;    // 0..7
      dma16(A + (long)(row0 + 16 * ch + srow) * lda + k0 + scol, (char*)As + ch * 1024);
      dma16(B + (long)(col0 + 16 * ch + srow) * ldb + k0 + scol, (char*)Bs + ch * 1024);
    }
    __syncthreads();               // drains DMA (vmcnt0)
    bf16x8 af[4], bfr[4];
#pragma unroll
    for (int i = 0; i < 4; i++) {
      af[i]  = *(const bf16x8*)(As + (wr * 64 + i * 16 + lm) * 32 + quad * 8);
      bfr[i] = *(const bf16x8*)(Bs + (wc * 64 + i * 16 + lm) * 32 + quad * 8);
    }
#pragma unroll
    for (int i = 0; i < 4; i++)
#pragma unroll
      for (int j = 0; j < 4; j++)
        acc[i][j] = __builtin_amdgcn_mfma_f32_16x16x32_bf16(af[i], bfr[j], acc[i][j], 0, 0, 0);
  }

  if constexpr (MODE == 3) {
    // transpose epilogue: C[128t x 128d] -> LDS (padded) -> coalesced C^T stores
    __shared__ alignas(16) bf16 Ts[128 * 136];   // [d][t], stride 136 (272B, 16B-aligned)
#pragma unroll
    for (int i = 0; i < 4; i++)
#pragma unroll
      for (int j = 0; j < 4; j++)
#pragma unroll
        for (int r = 0; r < 4; r++) {
          const int tl = wr * 64 + i * 16 + quad * 4 + r;
          const int cl = wc * 64 + j * 16 + lm;
          Ts[cl * 136 + tl] = (bf16)acc[i][j][r];
        }
    __syncthreads();
    bf16* Cb = (bf16*)Cv + (long)z * sC;
    const int t4 = (l & 31) * 4;                 // 4 bf16 = 8B per lane
#pragma unroll
    for (int pp = 0; pp < 16; pp++) {
      const int d = pp * 8 + w * 2 + (l >> 5);   // 128 d-rows over 16 passes
      *(uint2*)(Cb + (long)d * ldc + row0 + t4) = *(const uint2*)(Ts + d * 136 + t4);
    }
  } else {
#pragma unroll
    for (int i = 0; i < 4; i++) {
#pragma unroll
      for (int j = 0; j < 4; j++) {
#pragma unroll
        for (int r = 0; r < 4; r++) {
          float val = acc[i][j][r];
          float partner = __shfl_xor(val, 1, 64);  // unconditional: lane pair = adjacent column
          int rr = row0 + wr * 64 + i * 16 + quad * 4 + r;
          int cc = col0 + wc * 64 + j * 16 + lm;
          if (cc < N) {
            if (MODE == 0) {
              ((float*)Cv + (long)z * sC)[(long)rr * ldc + cc] = val;
            } else if (MODE == 1) {
              ((bf16*)Cv + (long)z * sC)[(long)rr * ldc + cc] = (bf16)val;
            } else {
              int s = rr & (SEQ - 1);
              int h = cc / 192, wi = cc % 192;
              if (wi < 128) {
                qn[((long)h * T_TOK + rr) * 128 + wi] = (bf16)(val * SM_SCALE);
              } else {
                int pp = (wi - 128) >> 1;
                float cs = freqs[s * 64 + pp * 2], sn = freqs[s * 64 + pp * 2 + 1];
                float res = ((wi & 1) == 0) ? (val * cs - partner * sn)
                                            : (partner * sn + val * cs);
                qabs[((long)h * T_TOK + rr) * 576 + 512 + (wi - 128)] = (bf16)(res * SM_SCALE);
              }
            }
          }
        }
      }
    }
  }
}

// ================= rmsnorm(kv) + rope(k_pe) -> K' bf16 (8192 x 576, ld=KLD) =================
__global__ __launch_bounds__(64) void kvnorm_rope(const float* __restrict__ kvf,
                                                  const float* __restrict__ wnorm,
                                                  const float* __restrict__ freqs,
                                                  bf16* __restrict__ Kp) {
  const int t = blockIdx.x, l = threadIdx.x, s = t & (SEQ - 1);
  const float* row = kvf + (long)t * 576;
  float4 a4 = ((const float4*)row)[l * 2];
  float4 b4 = ((const float4*)row)[l * 2 + 1];
  float v[8] = {a4.x, a4.y, a4.z, a4.w, b4.x, b4.y, b4.z, b4.w};
  float ssq = 0.f;
#pragma unroll
  for (int i = 0; i < 8; i++) ssq += v[i] * v[i];
#pragma unroll
  for (int m = 1; m < 64; m <<= 1) ssq += __shfl_xor(ssq, m, 64);
  const float rn = rsqrtf(ssq * (1.f / 512.f) + 1e-6f);
  bf16x8 o;
#pragma unroll
  for (int i = 0; i < 8; i++) o[i] = (bf16)(v[i] * rn * wnorm[l * 8 + i]);
  *(bf16x8*)(Kp + (long)t * KLD + l * 8) = o;
  if (l < 32) {
    float xr = row[512 + 2 * l], xi = row[513 + 2 * l];
    float cs = freqs[s * 64 + 2 * l], sn = freqs[s * 64 + 2 * l + 1];
    Kp[(long)t * KLD + 512 + 2 * l] = (bf16)(xr * cs - xi * sn);
    Kp[(long)t * KLD + 513 + 2 * l] = (bf16)(xr * sn + xi * cs);
  }
}

// ============================ flash MLA attention (v11) ============================
// v10 structure unchanged (producer/consumer wave roles, Ks dbuf, 2 raw barriers/iter,
// work-stealing). Only the sync primitives changed: no "memory" clobber (see sync_vm).
__global__ __attribute__((amdgpu_waves_per_eu(2, 2))) __launch_bounds__(512)
void mla_attn(const bf16* __restrict__ qabs,
              const bf16* __restrict__ Kp,
              const bf16* __restrict__ VpT,
              bf16* __restrict__ o_all,
              int* __restrict__ ctr) {
  constexpr int PROW = 36;                        // 32 + 4 pad (72B rows: odd dword stride)
  __shared__ alignas(16) bf16 Ks[2][20480];       // 2 x 40KB K-tile (40 x 1KB DMA chunks)
  __shared__ alignas(16) bf16 Ps[4 * 32 * PROW];  // P^T per head: [4h][32q][PROW]
  __shared__ float alpha_s[128];
  __shared__ float l_s[128];
  __shared__ int jid_s;

  const int tid = threadIdx.x, w = tid >> 6, l = tid & 63;
  const int lm = l & 15, quad = l >> 4;
  const bool isS = (w < 4);
  const int h4 = w & 3;                           // head index within group (both roles)

  for (;;) {
    __syncthreads();
    if (tid == 0) jid_s = atomicAdd(ctr, 1);
    __syncthreads();
    const int j = jid_s;
    if (j >= NJOBS) return;

    const int mac = 63 - j / 12;                  // 32-row q-macro, big-first (LPT)
    const int bg = j % 12;
    const int b = bg & 3, g = bg >> 2;
    const int nk = mac + 1;
    const long tq0 = (long)b * SEQ + mac * 32;
    const bf16* KpB = Kp + (long)b * SEQ * KLD;

    if (isS) {
      // ---------------- producer / S role ----------------
      bf16x8 qf[2][18];                           // both q-subtiles for this head (144 VGPR)
#pragma unroll
      for (int n = 0; n < 2; n++) {
        const bf16* qb =
            qabs + ((long)(g * 4 + h4) * T_TOK + tq0 + n * 16 + lm) * 576 + quad * 8;
#pragma unroll
        for (int kk = 0; kk < 18; kk++) qf[n][kk] = *(const bf16x8*)(qb + kk * 32);
      }
      float mstate[2] = {-__builtin_inff(), -__builtin_inff()};
      float lstate[2] = {0.f, 0.f};

      for (int kt = 0; kt < nk; kt++) {
        sync_vm();                                // K-DMA(kt) drained (issued by PV-waves)
        const bf16* Kcur = Ks[kt & 1];

        floatx4 sacc[2][2] = {};                  // [t-subtile][q-subtile]
#pragma unroll
        for (int kk = 0; kk < 18; kk++) {
          bf16x8 kf0 = *(const bf16x8*)(Kcur + lm * KLD + kk * 32 + quad * 8);
          bf16x8 kf1 = *(const bf16x8*)(Kcur + (16 + lm) * KLD + kk * 32 + quad * 8);
          sacc[0][0] = __builtin_amdgcn_mfma_f32_16x16x32_bf16(kf0, qf[0][kk], sacc[0][0], 0, 0, 0);
          sacc[0][1] = __builtin_amdgcn_mfma_f32_16x16x32_bf16(kf0, qf[1][kk], sacc[0][1], 0, 0, 0);
          sacc[1][0] = __builtin_amdgcn_mfma_f32_16x16x32_bf16(kf1, qf[0][kk], sacc[1][0], 0, 0, 0);
          sacc[1][1] = __builtin_amdgcn_mfma_f32_16x16x32_bf16(kf1, qf[1][kk], sacc[1][1], 0, 0, 0);
        }
        if (kt == nk - 1) {                       // causal diagonal 32x32
#pragma unroll
          for (int m = 0; m < 2; m++)
#pragma unroll
            for (int n = 0; n < 2; n++)
#pragma unroll
              for (int r = 0; r < 4; r++)
                if (m * 16 + quad * 4 + r > n * 16 + lm) sacc[m][n][r] = -__builtin_inff();
        }
        // online softmax per q-subtile (wave-local; stats replicated across quads via shfl)
#pragma unroll
        for (int n = 0; n < 2; n++) {
          float cmax = -__builtin_inff();
#pragma unroll
          for (int m = 0; m < 2; m++)
#pragma unroll
            for (int r = 0; r < 4; r++) cmax = fmaxf(cmax, sacc[m][n][r]);
          cmax = fmaxf(cmax, __shfl_xor(cmax, 16, 64));
          cmax = fmaxf(cmax, __shfl_xor(cmax, 32, 64));
          const float mnew = fmaxf(mstate[n], cmax);
          const float alpha = __expf(mstate[n] - mnew);
          float psum = 0.f;
#pragma unroll
          for (int m = 0; m < 2; m++) {
            bf16x4 pw;
#pragma unroll
            for (int r = 0; r < 4; r++) {
              float pv = __expf(sacc[m][n][r] - mnew);
              psum += pv;
              pw[r] = (bf16)pv;
            }
            *(bf16x4*)(Ps + (h4 * 32 + n * 16 + lm) * PROW + m * 16 + quad * 4) = pw;
          }
          psum += __shfl_xor(psum, 16, 64);
          psum += __shfl_xor(psum, 32, 64);
          lstate[n] = lstate[n] * alpha + psum;
          mstate[n] = mnew;
          if (quad == 0) alpha_s[h4 * 32 + n * 16 + lm] = alpha;
        }
        sync_lg();                                // Ps/alpha visible
      }
      if (quad == 0) {
        l_s[h4 * 32 + lm] = lstate[0];
        l_s[h4 * 32 + 16 + lm] = lstate[1];
      }
      __syncthreads();                            // l_s visible; epilogue done by PV-waves
    } else {
      // ---------------- consumer / PV role ----------------
      floatx4 oacc[2][8] = {};                    // [q-subtile][d-tile]; full 128d for head h4

      {  // prologue DMA of K-tile 0 -> Ks[0] (40 chunks over 4 PV-waves)
#pragma unroll
        for (int jj = 0; jj < 10; jj++)
          dma16((const char*)KpB + (h4 + jj * 4) * 1024 + l * 16,
                (char*)Ks[0] + (h4 + jj * 4) * 1024);
      }

      for (int kt = 0; kt < nk; kt++) {
        sync_vm();                                // own DMA drained; rendezvous with S
        // V loads FIRST (8 ops), then next-tile K-DMA (10 ops): vb use waits vmcnt(10),
        // never draining the DMA (in-order retirement: V are the oldest).
        bf16x8 vb[8];
        const long tv = (long)b * SEQ + kt * 32 + quad * 8;
#pragma unroll
        for (int dt = 0; dt < 8; dt++) {
          const bf16* vrow =
              VpT + ((long)((g * 4 + h4) * 128 + dt * 16 + lm)) * T_TOK + tv;
          vb[dt] = *(const bf16x8*)(vrow);
        }
        {  // next K-tile (last iter refetches current: dead but keeps counts uniform)
          const int ktn = (kt + 1 < nk) ? kt + 1 : kt;
          const char* gk = (const char*)(KpB + (long)ktn * 32 * KLD);
          char* ld = (char*)Ks[(kt + 1) & 1];
#pragma unroll
          for (int jj = 0; jj < 10; jj++)
            dma16(gk + (h4 + jj * 4) * 1024 + l * 16, ld + (h4 + jj * 4) * 1024);
        }
        sync_lg();                                // Ps/alpha of this kt now visible

        // PV: rescale O, then O += P^T(LDS) * V  (16 MFMAs: 2 q-subtiles x 8 d-tiles)
#pragma unroll
        for (int qt = 0; qt < 2; qt++) {
#pragma unroll
          for (int r = 0; r < 4; r++) {
            const float a = alpha_s[h4 * 32 + qt * 16 + quad * 4 + r];
#pragma unroll
            for (int dt = 0; dt < 8; dt++) oacc[qt][dt][r] *= a;
          }
          bf16x8 pa = *(const bf16x8*)(Ps + (h4 * 32 + qt * 16 + lm) * PROW + quad * 8);
#pragma unroll
          for (int dt = 0; dt < 8; dt++)
            oacc[qt][dt] =
                __builtin_amdgcn_mfma_f32_16x16x32_bf16(pa, vb[dt], oacc[qt][dt], 0, 0, 0);
        }
      }
      __syncthreads();                            // l_s visible (matches S epilogue barrier)

      // epilogue: scale by 1/l and store this head's full 32q x 128d
#pragma unroll
      for (int qt = 0; qt < 2; qt++) {
#pragma unroll
        for (int r = 0; r < 4; r++) {
          const int qrow = qt * 16 + quad * 4 + r;
          const float inv = 1.f / l_s[h4 * 32 + qrow];
#pragma unroll
          for (int dt = 0; dt < 8; dt++)
            o_all[(tq0 + qrow) * 1536 + (g * 4 + h4) * 128 + dt * 16 + lm] =
                (bf16)(oacc[qt][dt][r] * inv);
        }
      }
    }
    // steal-top __syncthreads (next job) separates all LDS reuse across jobs
  }
}

// ============================ launcher ============================
extern "C" void kernel_launch(void* const* d_in, const int* in_sizes, int n_in,
                              void* d_out, int out_size, void* d_ws, size_t ws_size,
                              hipStream_t stream) {
  (void)in_sizes; (void)n_in; (void)out_size; (void)ws_size;
  const float* x     = (const float*)d_in[0];
  const float* wq    = (const float*)d_in[1];
  const float* wkva  = (const float*)d_in[2];
  const float* kvnw  = (const float*)d_in[3];
  const float* wkvb  = (const float*)d_in[4];
  const float* wo    = (const float*)d_in[5];
  const float* freqs = (const float*)d_in[6];
  float* out = (float*)d_out;

  char* p = (char*)d_ws;
  auto alloc = [&](size_t bytes) {
    char* r = p;
    p += (bytes + 255) & ~(size_t)255;
    return r;
  };
  bf16*  xb    = (bf16*) alloc((size_t)T_TOK * 1024 * 2);
  bf16*  wqb   = (bf16*) alloc((size_t)2304 * 1024 * 2);
  bf16*  wkvab = (bf16*) alloc((size_t)640 * 1024 * 2);     // padded N 576->640
  bf16*  wbnT  = (bf16*) alloc((size_t)12 * 512 * 128 * 2);
  bf16*  wbv   = (bf16*) alloc((size_t)12 * 128 * 512 * 2);
  bf16*  wob   = (bf16*) alloc((size_t)1024 * 1536 * 2);
  float* kvf   = (float*)alloc((size_t)T_TOK * 576 * 4);
  bf16*  Kp    = (bf16*) alloc((size_t)T_TOK * KLD * 2 + 4096);  // +DMA slack (40KB-chunk overreach)
  bf16*  VpT   = (bf16*) alloc((size_t)12 * 128 * T_TOK * 2);
  bf16*  qn    = (bf16*) alloc((size_t)12 * T_TOK * 128 * 2);
  bf16*  qabs  = (bf16*) alloc((size_t)12 * T_TOK * 576 * 2);
  bf16*  o_all = (bf16*) alloc((size_t)T_TOK * 1536 * 2);
  int*   ctr   = (int*)  alloc(256);

  cast_f32_bf16<<<8192, 256, 0, stream>>>(x, xb, (long)T_TOK * 1024 / 4);
  cast_f32_bf16<<<2304, 256, 0, stream>>>(wq, wqb, (long)2304 * 1024 / 4);
  cast_wkva_pad<<<640, 256, 0, stream>>>(wkva, wkvab);
  split_wkvb<<<6144, 256, 0, stream>>>(wkvb, wbnT, wbv, ctr);
  cast_f32_bf16<<<1536, 256, 0, stream>>>(wo, wob, (long)1024 * 1536 / 4);

  // kv_full = x @ wkv_a^T  (fp32 out)
  gemm_bt<0><<<dim3(5, 64, 1), 256, 0, stream>>>(xb, wkvab, (void*)kvf, 576, 1024,
      1024, 1024, 576, 0, 0, 0, nullptr, nullptr, nullptr);
  // q = x @ wq^T, fused rope(q_pe)+scale epilogue -> qn, qabs[512:576]
  gemm_bt<2><<<dim3(18, 64, 1), 256, 0, stream>>>(xb, wqb, nullptr, 2304, 1024,
      1024, 1024, 0, 0, 0, 0, freqs, qn, qabs);
  kvnorm_rope<<<T_TOK, 64, 0, stream>>>(kvf, kvnw, freqs, Kp);
  // VpT[h][d][t] = (kv_c @ wbv[h]^T)^T  (batched over heads, transposed bf16 write)
  gemm_bt<3><<<dim3(1, 64, 12), 256, 0, stream>>>(Kp, wbv, (void*)VpT, 128, 512,
      KLD, 512, T_TOK, 0, (long)128 * 512, (long)128 * T_TOK,
      nullptr, nullptr, nullptr);
  // q_abs[h] = qn[h] @ wbnT[h]^T  (batched over heads, bf16 out into qabs[0:512])
  gemm_bt<1><<<dim3(4, 64, 12), 256, 0, stream>>>(qn, wbnT, (void*)qabs, 512, 128,
      128, 128, 576, (long)T_TOK * 128, (long)512 * 128, (long)T_TOK * 576,
      nullptr, nullptr, nullptr);
  mla_attn<<<dim3(256, 1, 1), 512, 0, stream>>>(qabs, Kp, VpT, o_all, ctr);
  // out = o_all @ wo^T (fp32 out)
  gemm_bt<0><<<dim3(8, 64, 1), 256, 0, stream>>>(o_all, wob, (void*)out, 1024, 1536,
      1536, 1536, 1024, 0, 0, 0, nullptr, nullptr, nullptr);
}

// Round 9
// 579.944 us; speedup vs baseline: 1.0065x; 1.0065x over previous
//
#include <hip/hip_runtime.h>

typedef __bf16 bf16;
typedef __bf16 bf16x8 __attribute__((ext_vector_type(8)));
typedef __bf16 bf16x4 __attribute__((ext_vector_type(4)));
typedef float floatx4 __attribute__((ext_vector_type(4)));

#define T_TOK 8192          // B*S tokens
#define SEQ 2048
#define KLD 584             // padded Kp leading dim (1168 B rows)
#define SM_SCALE 0.07216878364870323f   // 192^-0.5
#define NJOBS 768           // attn jobs: 4 b x 3 g x 64 q-macro32

// async global->LDS, 16B per lane; LDS dest is wave-uniform base + lane*16 (linear),
// global source address is per-lane.
__device__ __forceinline__ void dma16(const void* g, void* l) {
  __builtin_amdgcn_global_load_lds(
      (const __attribute__((address_space(1))) unsigned int*)g,
      (__attribute__((address_space(3))) unsigned int*)l, 16, 0, 0);
}

// single rendezvous barrier: drain own VMEM (DMA handoff) + own LDS ops, then barrier.
// sched_barrier(0) fences pin ordering (rule 18); no "memory" clobber.
__device__ __forceinline__ void sync_all() {
  __builtin_amdgcn_sched_barrier(0);
  asm volatile("s_waitcnt vmcnt(0) lgkmcnt(0)");
  __builtin_amdgcn_s_barrier();
  __builtin_amdgcn_sched_barrier(0);
}

// ============================ prep kernels ============================
__global__ __launch_bounds__(256) void cast_f32_bf16(const float* __restrict__ in,
                                                     bf16* __restrict__ out, long n4) {
  long i = (long)blockIdx.x * 256 + threadIdx.x;
  if (i >= n4) return;
  float4 v = ((const float4*)in)[i];
  bf16x4 o;
  o[0] = (bf16)v.x; o[1] = (bf16)v.y; o[2] = (bf16)v.z; o[3] = (bf16)v.w;
  ((bf16x4*)out)[i] = o;
}

// wkv_a (576,1024) -> bf16 padded to (640,1024), pad rows zeroed
__global__ __launch_bounds__(256) void cast_wkva_pad(const float* __restrict__ in,
                                                     bf16* __restrict__ out) {
  long i = (long)blockIdx.x * 256 + threadIdx.x;   // 4-elem chunks, 640*256 total
  int r = (int)(i >> 8);
  bf16x4 o;
  if (r < 576) {
    float4 v = ((const float4*)in)[i];
    o[0] = (bf16)v.x; o[1] = (bf16)v.y; o[2] = (bf16)v.z; o[3] = (bf16)v.w;
  } else {
    o[0] = (bf16)0.f; o[1] = (bf16)0.f; o[2] = (bf16)0.f; o[3] = (bf16)0.f;
  }
  ((bf16x4*)out)[i] = o;
}

// wkv_b (12*256, 512): d<128 -> wbnT[h][c][d] (transposed), d>=128 -> wbv[h][d-128][c]
// also zeroes the attn job counter (stream-ordered well before mla_attn)
__global__ __launch_bounds__(256) void split_wkvb(const float* __restrict__ in,
                                                  bf16* __restrict__ wbnT,
                                                  bf16* __restrict__ wbv,
                                                  int* __restrict__ ctr) {
  if (blockIdx.x == 0 && threadIdx.x == 0) *ctr = 0;
  int i = blockIdx.x * 256 + threadIdx.x;          // < 12*256*512
  int h = i >> 17, rem = i & 131071, d = rem >> 9, c = rem & 511;
  bf16 v = (bf16)in[i];
  if (d < 128) wbnT[((h * 512 + c) << 7) + d] = v;
  else         wbv[((h * 128 + (d - 128)) << 9) + c] = v;
}

// ============================ GEMM: C[M,N] = A[M,K] * B[N,K]^T ============================
// Staging via global_load_lds (m97 pattern). MODE 0: fp32 C. MODE 1: bf16 C.
// MODE 2: q-epilogue (rope q_pe -> qabs, scale q_nope -> qn).
// MODE 3: bf16 C^T via LDS transpose (coalesced 8B stores, was 2B scatter).
template <int MODE>
__global__ __launch_bounds__(256) void gemm_bt(
    const bf16* __restrict__ A, const bf16* __restrict__ B, void* __restrict__ Cv,
    int N, int K, int lda, int ldb, int ldc,
    long sA, long sB, long sC,
    const float* __restrict__ freqs, bf16* __restrict__ qn, bf16* __restrict__ qabs) {
  __shared__ alignas(16) bf16 As[128 * 32];
  __shared__ alignas(16) bf16 Bs[128 * 32];
  const int z = blockIdx.z;
  A += (long)z * sA;  B += (long)z * sB;
  const int row0 = blockIdx.y * 128, col0 = blockIdx.x * 128;
  const int tid = threadIdx.x;
  const int w = tid >> 6, l = tid & 63, lm = l & 15, quad = l >> 4;
  const int wr = w >> 1, wc = w & 1;
  floatx4 acc[4][4] = {};

  // per-lane source geometry for dma16 staging: chunk ch covers rows 16ch..16ch+15,
  // lane l -> row 16ch + (l>>2), elem col (l&3)*8 (16B per lane, LDS linear)
  const int srow = l >> 2, scol = (l & 3) * 8;

  for (int k0 = 0; k0 < K; k0 += 32) {
    __syncthreads();
#pragma unroll
    for (int c = 0; c < 2; c++) {
      const int ch = w * 2 + c;    // 0..7
      dma16(A + (long)(row0 + 16 * ch + srow) * lda + k0 + scol, (char*)As + ch * 1024);
      dma16(B + (long)(col0 + 16 * ch + srow) * ldb + k0 + scol, (char*)Bs + ch * 1024);
    }
    __syncthreads();               // drains DMA (vmcnt0)
    bf16x8 af[4], bfr[4];
#pragma unroll
    for (int i = 0; i < 4; i++) {
      af[i]  = *(const bf16x8*)(As + (wr * 64 + i * 16 + lm) * 32 + quad * 8);
      bfr[i] = *(const bf16x8*)(Bs + (wc * 64 + i * 16 + lm) * 32 + quad * 8);
    }
#pragma unroll
    for (int i = 0; i < 4; i++)
#pragma unroll
      for (int j = 0; j < 4; j++)
        acc[i][j] = __builtin_amdgcn_mfma_f32_16x16x32_bf16(af[i], bfr[j], acc[i][j], 0, 0, 0);
  }

  if constexpr (MODE == 3) {
    // transpose epilogue: C[128t x 128d] -> LDS (padded) -> coalesced C^T stores
    __shared__ alignas(16) bf16 Ts[128 * 136];   // [d][t], stride 136 (272B, 16B-aligned)
#pragma unroll
    for (int i = 0; i < 4; i++)
#pragma unroll
      for (int j = 0; j < 4; j++)
#pragma unroll
        for (int r = 0; r < 4; r++) {
          const int tl = wr * 64 + i * 16 + quad * 4 + r;
          const int cl = wc * 64 + j * 16 + lm;
          Ts[cl * 136 + tl] = (bf16)acc[i][j][r];
        }
    __syncthreads();
    bf16* Cb = (bf16*)Cv + (long)z * sC;
    const int t4 = (l & 31) * 4;                 // 4 bf16 = 8B per lane
#pragma unroll
    for (int pp = 0; pp < 16; pp++) {
      const int d = pp * 8 + w * 2 + (l >> 5);   // 128 d-rows over 16 passes
      *(uint2*)(Cb + (long)d * ldc + row0 + t4) = *(const uint2*)(Ts + d * 136 + t4);
    }
  } else {
#pragma unroll
    for (int i = 0; i < 4; i++) {
#pragma unroll
      for (int j = 0; j < 4; j++) {
#pragma unroll
        for (int r = 0; r < 4; r++) {
          float val = acc[i][j][r];
          float partner = __shfl_xor(val, 1, 64);  // unconditional: lane pair = adjacent column
          int rr = row0 + wr * 64 + i * 16 + quad * 4 + r;
          int cc = col0 + wc * 64 + j * 16 + lm;
          if (cc < N) {
            if (MODE == 0) {
              ((float*)Cv + (long)z * sC)[(long)rr * ldc + cc] = val;
            } else if (MODE == 1) {
              ((bf16*)Cv + (long)z * sC)[(long)rr * ldc + cc] = (bf16)val;
            } else {
              int s = rr & (SEQ - 1);
              int h = cc / 192, wi = cc % 192;
              if (wi < 128) {
                qn[((long)h * T_TOK + rr) * 128 + wi] = (bf16)(val * SM_SCALE);
              } else {
                int pp = (wi - 128) >> 1;
                float cs = freqs[s * 64 + pp * 2], sn = freqs[s * 64 + pp * 2 + 1];
                float res = ((wi & 1) == 0) ? (val * cs - partner * sn)
                                            : (partner * sn + val * cs);
                qabs[((long)h * T_TOK + rr) * 576 + 512 + (wi - 128)] = (bf16)(res * SM_SCALE);
              }
            }
          }
        }
      }
    }
  }
}

// ================= rmsnorm(kv) + rope(k_pe) -> K' bf16 (8192 x 576, ld=KLD) =================
__global__ __launch_bounds__(64) void kvnorm_rope(const float* __restrict__ kvf,
                                                  const float* __restrict__ wnorm,
                                                  const float* __restrict__ freqs,
                                                  bf16* __restrict__ Kp) {
  const int t = blockIdx.x, l = threadIdx.x, s = t & (SEQ - 1);
  const float* row = kvf + (long)t * 576;
  float4 a4 = ((const float4*)row)[l * 2];
  float4 b4 = ((const float4*)row)[l * 2 + 1];
  float v[8] = {a4.x, a4.y, a4.z, a4.w, b4.x, b4.y, b4.z, b4.w};
  float ssq = 0.f;
#pragma unroll
  for (int i = 0; i < 8; i++) ssq += v[i] * v[i];
#pragma unroll
  for (int m = 1; m < 64; m <<= 1) ssq += __shfl_xor(ssq, m, 64);
  const float rn = rsqrtf(ssq * (1.f / 512.f) + 1e-6f);
  bf16x8 o;
#pragma unroll
  for (int i = 0; i < 8; i++) o[i] = (bf16)(v[i] * rn * wnorm[l * 8 + i]);
  *(bf16x8*)(Kp + (long)t * KLD + l * 8) = o;
  if (l < 32) {
    float xr = row[512 + 2 * l], xi = row[513 + 2 * l];
    float cs = freqs[s * 64 + 2 * l], sn = freqs[s * 64 + 2 * l + 1];
    Kp[(long)t * KLD + 512 + 2 * l] = (bf16)(xr * cs - xi * sn);
    Kp[(long)t * KLD + 513 + 2 * l] = (bf16)(xr * sn + xi * cs);
  }
}

// ============================ flash MLA attention (v12) ============================
// Cross-role software pipeline, ONE barrier per iteration:
//   iter kt:  S-waves compute S(kt) from Ks[kt&1] -> Ps[kt&1], alpha_s[kt&1]
//          || PV-waves: load V(kt-1), DMA K(kt+1)->Ks[(kt+1)&1],
//                       rescale+PV from Ps[(kt-1)&1]/alpha_s[(kt-1)&1]
//   sync_all (vmcnt0+lgkm0+barrier): DMA drained (covered by the WHOLE iteration),
//   Ps(kt) visible for PV at iter kt+1.
// Hazards: all same-iter buffer parities disjoint; every cross-parity reuse separated
// by the iteration barrier. Barrier counts match across roles (pre-loop 1, loop nk,
// post-loop 1). v11's two-barrier scheme serialized S and PV phases (sum ~6150
// cyc/iter); this overlaps them (target ~max ~3000).
__global__ __attribute__((amdgpu_waves_per_eu(2, 2))) __launch_bounds__(512)
void mla_attn(const bf16* __restrict__ qabs,
              const bf16* __restrict__ Kp,
              const bf16* __restrict__ VpT,
              bf16* __restrict__ o_all,
              int* __restrict__ ctr) {
  constexpr int PROW = 36;                        // 32 + 4 pad (72B rows: odd dword stride)
  __shared__ alignas(16) bf16 Ks[2][20480];       // 2 x 40KB K-tile (40 x 1KB DMA chunks)
  __shared__ alignas(16) bf16 Ps[2][4 * 32 * PROW];  // dbuf P^T per head
  __shared__ float alpha_s[2][128];
  __shared__ float l_s[128];
  __shared__ int jid_s;

  const int tid = threadIdx.x, w = tid >> 6, l = tid & 63;
  const int lm = l & 15, quad = l >> 4;
  const bool isS = (w < 4);
  const int h4 = w & 3;                           // head index within group (both roles)

  for (;;) {
    __syncthreads();
    if (tid == 0) jid_s = atomicAdd(ctr, 1);
    __syncthreads();
    const int j = jid_s;
    if (j >= NJOBS) return;

    const int mac = 63 - j / 12;                  // 32-row q-macro, big-first (LPT)
    const int bg = j % 12;
    const int b = bg & 3, g = bg >> 2;
    const int nk = mac + 1;
    const long tq0 = (long)b * SEQ + mac * 32;
    const bf16* KpB = Kp + (long)b * SEQ * KLD;

    if (isS) {
      // ---------------- producer / S role ----------------
      bf16x8 qf[2][18];                           // both q-subtiles for this head
#pragma unroll
      for (int n = 0; n < 2; n++) {
        const bf16* qb =
            qabs + ((long)(g * 4 + h4) * T_TOK + tq0 + n * 16 + lm) * 576 + quad * 8;
#pragma unroll
        for (int kk = 0; kk < 18; kk++) qf[n][kk] = *(const bf16x8*)(qb + kk * 32);
      }
      float mstate[2] = {-__builtin_inff(), -__builtin_inff()};
      float lstate[2] = {0.f, 0.f};

      sync_all();                                 // pre-loop: K(0) DMA drained

      for (int kt = 0; kt < nk; kt++) {
        const bf16* Kcur = Ks[kt & 1];
        bf16* Pcur = Ps[kt & 1];
        float* Acur = alpha_s[kt & 1];

        floatx4 sacc[2][2] = {};                  // [t-subtile][q-subtile]
#pragma unroll
        for (int kk = 0; kk < 18; kk++) {
          bf16x8 kf0 = *(const bf16x8*)(Kcur + lm * KLD + kk * 32 + quad * 8);
          bf16x8 kf1 = *(const bf16x8*)(Kcur + (16 + lm) * KLD + kk * 32 + quad * 8);
          sacc[0][0] = __builtin_amdgcn_mfma_f32_16x16x32_bf16(kf0, qf[0][kk], sacc[0][0], 0, 0, 0);
          sacc[0][1] = __builtin_amdgcn_mfma_f32_16x16x32_bf16(kf0, qf[1][kk], sacc[0][1], 0, 0, 0);
          sacc[1][0] = __builtin_amdgcn_mfma_f32_16x16x32_bf16(kf1, qf[0][kk], sacc[1][0], 0, 0, 0);
          sacc[1][1] = __builtin_amdgcn_mfma_f32_16x16x32_bf16(kf1, qf[1][kk], sacc[1][1], 0, 0, 0);
        }
        if (kt == nk - 1) {                       // causal diagonal 32x32
#pragma unroll
          for (int m = 0; m < 2; m++)
#pragma unroll
            for (int n = 0; n < 2; n++)
#pragma unroll
              for (int r = 0; r < 4; r++)
                if (m * 16 + quad * 4 + r > n * 16 + lm) sacc[m][n][r] = -__builtin_inff();
        }
        // online softmax per q-subtile (wave-local; stats replicated across quads via shfl)
#pragma unroll
        for (int n = 0; n < 2; n++) {
          float cmax = -__builtin_inff();
#pragma unroll
          for (int m = 0; m < 2; m++)
#pragma unroll
            for (int r = 0; r < 4; r++) cmax = fmaxf(cmax, sacc[m][n][r]);
          cmax = fmaxf(cmax, __shfl_xor(cmax, 16, 64));
          cmax = fmaxf(cmax, __shfl_xor(cmax, 32, 64));
          const float mnew = fmaxf(mstate[n], cmax);
          const float alpha = __expf(mstate[n] - mnew);
          float psum = 0.f;
#pragma unroll
          for (int m = 0; m < 2; m++) {
            bf16x4 pw;
#pragma unroll
            for (int r = 0; r < 4; r++) {
              float pv = __expf(sacc[m][n][r] - mnew);
              psum += pv;
              pw[r] = (bf16)pv;
            }
            *(bf16x4*)(Pcur + (h4 * 32 + n * 16 + lm) * PROW + m * 16 + quad * 4) = pw;
          }
          psum += __shfl_xor(psum, 16, 64);
          psum += __shfl_xor(psum, 32, 64);
          lstate[n] = lstate[n] * alpha + psum;
          mstate[n] = mnew;
          if (quad == 0) Acur[h4 * 32 + n * 16 + lm] = alpha;
        }
        sync_all();                               // Ps(kt)/alpha(kt) visible; DMA(kt+1) drained
      }
      if (quad == 0) {
        l_s[h4 * 32 + lm] = lstate[0];
        l_s[h4 * 32 + 16 + lm] = lstate[1];
      }
      __syncthreads();                            // l_s visible; PV does epilogue stores
    } else {
      // ---------------- consumer / PV role ----------------
      floatx4 oacc[2][8] = {};                    // [q-subtile][d-tile]; full 128d for head h4

      {  // prologue DMA of K-tile 0 -> Ks[0] (40 chunks over 4 PV-waves)
#pragma unroll
        for (int jj = 0; jj < 10; jj++)
          dma16((const char*)KpB + (h4 + jj * 4) * 1024 + l * 16,
                (char*)Ks[0] + (h4 + jj * 4) * 1024);
      }
      sync_all();                                 // pre-loop rendezvous (K(0) drained)

      for (int kt = 0; kt < nk; kt++) {
        // V(kt-1) loads first (oldest VMEM: consumed at vmcnt(10), before DMA drain)
        bf16x8 vb[8];
        if (kt > 0) {
          const long tv = (long)b * SEQ + (kt - 1) * 32 + quad * 8;
#pragma unroll
          for (int dt = 0; dt < 8; dt++) {
            const bf16* vrow =
                VpT + ((long)((g * 4 + h4) * 128 + dt * 16 + lm)) * T_TOK + tv;
            vb[dt] = *(const bf16x8*)(vrow);
          }
        }
        {  // DMA K(kt+1) (clamped; last iter re-DMAs current into the dead buffer)
          const int ktn = (kt + 1 < nk) ? kt + 1 : kt;
          const char* gk = (const char*)(KpB + (long)ktn * 32 * KLD);
          char* ld = (char*)Ks[(kt + 1) & 1];
#pragma unroll
          for (int jj = 0; jj < 10; jj++)
            dma16(gk + (h4 + jj * 4) * 1024 + l * 16, ld + (h4 + jj * 4) * 1024);
        }
        if (kt > 0) {
          // PV(kt-1): rescale O by alpha(kt-1), then O += P^T(kt-1) * V(kt-1)
          const bf16* Pprev = Ps[(kt - 1) & 1];
          const float* Aprev = alpha_s[(kt - 1) & 1];
#pragma unroll
          for (int qt = 0; qt < 2; qt++) {
#pragma unroll
            for (int r = 0; r < 4; r++) {
              const float a = Aprev[h4 * 32 + qt * 16 + quad * 4 + r];
#pragma unroll
              for (int dt = 0; dt < 8; dt++) oacc[qt][dt][r] *= a;
            }
            bf16x8 pa = *(const bf16x8*)(Pprev + (h4 * 32 + qt * 16 + lm) * PROW + quad * 8);
#pragma unroll
            for (int dt = 0; dt < 8; dt++)
              oacc[qt][dt] =
                  __builtin_amdgcn_mfma_f32_16x16x32_bf16(pa, vb[dt], oacc[qt][dt], 0, 0, 0);
          }
        }
        sync_all();                               // drains DMA(kt+1); Ps(kt) now visible
      }

      {  // tail: PV(nk-1) (Ps/alpha visible from loop-final barrier)
        bf16x8 vb[8];
        const long tv = (long)b * SEQ + (nk - 1) * 32 + quad * 8;
#pragma unroll
        for (int dt = 0; dt < 8; dt++) {
          const bf16* vrow =
              VpT + ((long)((g * 4 + h4) * 128 + dt * 16 + lm)) * T_TOK + tv;
          vb[dt] = *(const bf16x8*)(vrow);
        }
        const bf16* Pprev = Ps[(nk - 1) & 1];
        const float* Aprev = alpha_s[(nk - 1) & 1];
#pragma unroll
        for (int qt = 0; qt < 2; qt++) {
#pragma unroll
          for (int r = 0; r < 4; r++) {
            const float a = Aprev[h4 * 32 + qt * 16 + quad * 4 + r];
#pragma unroll
            for (int dt = 0; dt < 8; dt++) oacc[qt][dt][r] *= a;
          }
          bf16x8 pa = *(const bf16x8*)(Pprev + (h4 * 32 + qt * 16 + lm) * PROW + quad * 8);
#pragma unroll
          for (int dt = 0; dt < 8; dt++)
            oacc[qt][dt] =
                __builtin_amdgcn_mfma_f32_16x16x32_bf16(pa, vb[dt], oacc[qt][dt], 0, 0, 0);
        }
      }
      __syncthreads();                            // l_s visible (matches S epilogue barrier)

      // epilogue: scale by 1/l and store this head's full 32q x 128d
#pragma unroll
      for (int qt = 0; qt < 2; qt++) {
#pragma unroll
        for (int r = 0; r < 4; r++) {
          const int qrow = qt * 16 + quad * 4 + r;
          const float inv = 1.f / l_s[h4 * 32 + qrow];
#pragma unroll
          for (int dt = 0; dt < 8; dt++)
            o_all[(tq0 + qrow) * 1536 + (g * 4 + h4) * 128 + dt * 16 + lm] =
                (bf16)(oacc[qt][dt][r] * inv);
        }
      }
    }
    // steal-top __syncthreads (next job) separates all LDS reuse across jobs
  }
}

// ============================ launcher ============================
extern "C" void kernel_launch(void* const* d_in, const int* in_sizes, int n_in,
                              void* d_out, int out_size, void* d_ws, size_t ws_size,
                              hipStream_t stream) {
  (void)in_sizes; (void)n_in; (void)out_size; (void)ws_size;
  const float* x     = (const float*)d_in[0];
  const float* wq    = (const float*)d_in[1];
  const float* wkva  = (const float*)d_in[2];
  const float* kvnw  = (const float*)d_in[3];
  const float* wkvb  = (const float*)d_in[4];
  const float* wo    = (const float*)d_in[5];
  const float* freqs = (const float*)d_in[6];
  float* out = (float*)d_out;

  char* p = (char*)d_ws;
  auto alloc = [&](size_t bytes) {
    char* r = p;
    p += (bytes + 255) & ~(size_t)255;
    return r;
  };
  bf16*  xb    = (bf16*) alloc((size_t)T_TOK * 1024 * 2);
  bf16*  wqb   = (bf16*) alloc((size_t)2304 * 1024 * 2);
  bf16*  wkvab = (bf16*) alloc((size_t)640 * 1024 * 2);     // padded N 576->640
  bf16*  wbnT  = (bf16*) alloc((size_t)12 * 512 * 128 * 2);
  bf16*  wbv   = (bf16*) alloc((size_t)12 * 128 * 512 * 2);
  bf16*  wob   = (bf16*) alloc((size_t)1024 * 1536 * 2);
  float* kvf   = (float*)alloc((size_t)T_TOK * 576 * 4);
  bf16*  Kp    = (bf16*) alloc((size_t)T_TOK * KLD * 2 + 4096);  // +DMA slack (40KB-chunk overreach)
  bf16*  VpT   = (bf16*) alloc((size_t)12 * 128 * T_TOK * 2);
  bf16*  qn    = (bf16*) alloc((size_t)12 * T_TOK * 128 * 2);
  bf16*  qabs  = (bf16*) alloc((size_t)12 * T_TOK * 576 * 2);
  bf16*  o_all = (bf16*) alloc((size_t)T_TOK * 1536 * 2);
  int*   ctr   = (int*)  alloc(256);

  cast_f32_bf16<<<8192, 256, 0, stream>>>(x, xb, (long)T_TOK * 1024 / 4);
  cast_f32_bf16<<<2304, 256, 0, stream>>>(wq, wqb, (long)2304 * 1024 / 4);
  cast_wkva_pad<<<640, 256, 0, stream>>>(wkva, wkvab);
  split_wkvb<<<6144, 256, 0, stream>>>(wkvb, wbnT, wbv, ctr);
  cast_f32_bf16<<<1536, 256, 0, stream>>>(wo, wob, (long)1024 * 1536 / 4);

  // kv_full = x @ wkv_a^T  (fp32 out)
  gemm_bt<0><<<dim3(5, 64, 1), 256, 0, stream>>>(xb, wkvab, (void*)kvf, 576, 1024,
      1024, 1024, 576, 0, 0, 0, nullptr, nullptr, nullptr);
  // q = x @ wq^T, fused rope(q_pe)+scale epilogue -> qn, qabs[512:576]
  gemm_bt<2><<<dim3(18, 64, 1), 256, 0, stream>>>(xb, wqb, nullptr, 2304, 1024,
      1024, 1024, 0, 0, 0, 0, freqs, qn, qabs);
  kvnorm_rope<<<T_TOK, 64, 0, stream>>>(kvf, kvnw, freqs, Kp);
  // VpT[h][d][t] = (kv_c @ wbv[h]^T)^T  (batched over heads, transposed bf16 write)
  gemm_bt<3><<<dim3(1, 64, 12), 256, 0, stream>>>(Kp, wbv, (void*)VpT, 128, 512,
      KLD, 512, T_TOK, 0, (long)128 * 512, (long)128 * T_TOK,
      nullptr, nullptr, nullptr);
  // q_abs[h] = qn[h] @ wbnT[h]^T  (batched over heads, bf16 out into qabs[0:512])
  gemm_bt<1><<<dim3(4, 64, 12), 256, 0, stream>>>(qn, wbnT, (void*)qabs, 512, 128,
      128, 128, 576, (long)T_TOK * 128, (long)512 * 128, (long)T_TOK * 576,
      nullptr, nullptr, nullptr);
  mla_attn<<<dim3(256, 1, 1), 512, 0, stream>>>(qabs, Kp, VpT, o_all, ctr);
  // out = o_all @ wo^T (fp32 out)
  gemm_bt<0><<<dim3(8, 64, 1), 256, 0, stream>>>(o_all, wob, (void*)out, 1024, 1536,
      1536, 1536, 1024, 0, 0, 0, nullptr, nullptr, nullptr);
}